// Round 7
// baseline (198.744 us; speedup 1.0000x reference)
//
#include <hip/hip_runtime.h>
#include <math.h>
#include <stdint.h>

#define NUMCH 65
#define THREADS 256
#define WAVES 4
#define NTILE 2
#define CTILE 1024
#define TILE_T 2048
#define NGRP 32
#define PLEN 768
#define MAXP 256
#define NCMAX 52

// LDS geometry (dwords)
#define XDW 1464        // logical x-window dwords (2 bf16 el/dword)
#define XPLANE 1792     // phys (SW4-swizzled) plane, padded to 7*256
#define XINSTS 7        // width-16 DMA insts per plane
#define XSLOTMAX 410    // last valid phys 16B slot
#define WBDW 896        // w-band dwords (14*64)
#define WINSTS 14
#define BUFDW (2 * XPLANE + WBDW)   // 4480
#define SMEMDW (2 * BUFDW)          // 8960 dw = 35.8 KB
#define RSTRIDE 1184

struct PTab {
  short c[MAXP], ka[MAXP], nc[MAXP];
  int start[NGRP + 1];
};

typedef short bf16x8 __attribute__((ext_vector_type(8)));
typedef float f32x16 __attribute__((ext_vector_type(16)));
typedef const __attribute__((address_space(1))) uint32_t* gptr_t;
typedef __attribute__((address_space(3))) uint32_t* sptr_t;

__global__ void zero_kernel(float* __restrict__ out, int n)
{
  int i = blockIdx.x * blockDim.x + threadIdx.x;
  if (i < n) out[i] = 0.0f;
}

__device__ __forceinline__ uint32_t f2bf(float f) {
  uint32_t u = __float_as_uint(f);
  return (u + 0x7FFFu + ((u >> 16) & 1u)) >> 16;
}
__device__ __forceinline__ void splithl(float v, uint32_t& h, uint32_t& l) {
  h = f2bf(v);
  l = f2bf(v - __uint_as_float(h << 16));
}
__device__ __forceinline__ uint32_t packhl(float v) {
  uint32_t h, l;
  splithl(v, h, l);
  return h | (l << 16);
}

// ---- phase 1: precompute bf16 h/l planes for x (zero-padded margins) ----
__global__ void prep_x(const float* __restrict__ inp, uint32_t* __restrict__ xh,
                       uint32_t* __restrict__ xl, int T, int rowdw, int PL)
{
  const int row = blockIdx.y;                               // b*65+c
  const int d = blockIdx.x * blockDim.x + threadIdx.x;      // dword in row
  if (d >= rowdw) return;
  const int b = row / NUMCH, c = row % NUMCH;
  const float* xr = inp + ((size_t)b * (2 * NUMCH) + c) * T;
  const int t0 = 2 * d - PL;
  const float v0 = (t0 >= 0 && t0 < T) ? xr[t0] : 0.0f;
  const float v1 = (t0 + 1 >= 0 && t0 + 1 < T) ? xr[t0 + 1] : 0.0f;
  uint32_t h0, l0, h1, l1;
  splithl(v0, h0, l0);
  splithl(v1, h1, l1);
  xh[(size_t)row * rowdw + d] = h0 | (h1 << 16);
  xl[(size_t)row * rowdw + d] = l0 | (l1 << 16);
}

// ---- phase 1: w -> hl dword plane (zero-padded) ----
__global__ void prep_w(const float* __restrict__ w, uint32_t* __restrict__ whl, int K, int wrow)
{
  const int i = blockIdx.x * blockDim.x + threadIdx.x;
  const int c = blockIdx.y;
  if (i >= wrow) return;
  const int k = i - 64;
  const float v = (k >= 0 && k < K) ? w[(size_t)c * K + k] : 0.0f;
  whl[(size_t)c * wrow + i] = packhl(v);
}

// ---- async DMA staging of one piece into an LDS buffer ----
__device__ __forceinline__ void issue_piece(const uint32_t* __restrict__ xhp,
                                            const uint32_t* __restrict__ xlp,
                                            const uint32_t* __restrict__ whlp,
                                            int xbase, int wq0, uint32_t* buf,
                                            int wv, int lane)
{
  uint32_t* bxh = buf;
  uint32_t* bxl = buf + XPLANE;
  uint32_t* bwb = buf + 2 * XPLANE;
  #pragma unroll
  for (int i = 0; i < XINSTS; ++i) {
    if ((i & 3) != wv) continue;                 // round-robin insts over waves
    int u = 64 * i + lane;
    if (u > XSLOTMAX) u = XSLOTMAX;
    const int m = u - (u + 1) / 9;               // phys 16B slot -> logical 16B group
    __builtin_amdgcn_global_load_lds((gptr_t)(xhp + xbase + 4 * m), (sptr_t)(bxh + 256 * i), 16, 0, 0);
    __builtin_amdgcn_global_load_lds((gptr_t)(xlp + xbase + 4 * m), (sptr_t)(bxl + 256 * i), 16, 0, 0);
  }
  #pragma unroll
  for (int i = 0; i < WINSTS; ++i) {
    if ((i & 3) != wv) continue;
    const int d = 64 * i + lane;
    __builtin_amdgcn_global_load_lds((gptr_t)(whlp + wq0 + d), (sptr_t)(bwb + 64 * i), 4, 0, 0);
  }
}

// ---- MFMA inner loop over one staged piece ----
__device__ __forceinline__ void compute_piece(int nc, const uint32_t* bxh, const uint32_t* bxl,
                                              const uint32_t* bwb, f32x16* acc,
                                              int col, int half, int wv)
{
  for (int ci = wv; ci < nc; ci += WAVES) {
    const int abase = 32 + 16 * ci + 8 * half - col;
    uint32_t ad[8];
    #pragma unroll
    for (int j = 0; j < 8; ++j) ad[j] = bwb[abase + j];
    union AU { uint32_t u[4]; bf16x8 v; } Ah, Al;
    #pragma unroll
    for (int j = 0; j < 4; ++j) {
      const uint32_t a0 = ad[2 * j], a1 = ad[2 * j + 1];
      Ah.u[j] = (a0 & 0xFFFFu) | (a1 << 16);
      Al.u[j] = (a0 >> 16) | (a1 & 0xFFFF0000u);
    }
    const int dbase = 16 * col + 8 * ci + 4 * half;
    #pragma unroll
    for (int tau = 0; tau < NTILE; ++tau) {
      const int d0 = 512 * tau + dbase;
      const int p0 = d0 + ((d0 >> 5) << 2);      // SW4
      union BU { uint4 q; bf16x8 v; } Bh, Bl;
      Bh.q = *(const uint4*)&bxh[p0];
      Bl.q = *(const uint4*)&bxl[p0];
      acc[tau] = __builtin_amdgcn_mfma_f32_32x32x16_bf16(Ah.v, Bh.v, acc[tau], 0, 0, 0);
      acc[tau] = __builtin_amdgcn_mfma_f32_32x32x16_bf16(Ah.v, Bl.v, acc[tau], 0, 0, 0);
      acc[tau] = __builtin_amdgcn_mfma_f32_32x32x16_bf16(Al.v, Bh.v, acc[tau], 0, 0, 0);
    }
  }
}

__device__ __forceinline__ void epilogue(uint32_t* smem, f32x16* acc, float* __restrict__ out,
                                         size_t outbase, float inv_fs, int tid, int col, int half, int wv)
{
  #pragma unroll
  for (int tau = 0; tau < NTILE; ++tau) {
    #pragma unroll
    for (int r = 0; r < 16; ++r) {
      const int row = (r & 3) + 8 * (r >> 2) + 4 * half;   // verified C/D layout
      const int tl = 32 * col + row;
      smem[wv * RSTRIDE + tl + (tl >> 5) * 5] = __float_as_uint(acc[tau][r]);
    }
    __syncthreads();
    for (int i = tid; i < CTILE; i += THREADS) {
      const int p = i + (i >> 5) * 5;
      float s = __uint_as_float(smem[p]) + __uint_as_float(smem[RSTRIDE + p]) +
                __uint_as_float(smem[2 * RSTRIDE + p]) + __uint_as_float(smem[3 * RSTRIDE + p]);
      atomicAdd(&out[outbase + tau * CTILE + i], s * inv_fs);
    }
    __syncthreads();
  }
}

// ---- main kernel: DMA-staged, double-buffered ----
__global__ __launch_bounds__(THREADS, 4)
void conv_dma(const uint32_t* __restrict__ xhp, const uint32_t* __restrict__ xlp,
              const uint32_t* __restrict__ whlp, const int* __restrict__ gidx,
              const int* __restrict__ fsp, float* __restrict__ out, PTab P,
              int B, int T, int K, int rowdw, int wrow, int PL)
{
  __shared__ __align__(16) uint32_t smem[SMEMDW];
  const int g = blockIdx.x, tg = blockIdx.y, b = blockIdx.z;
  const int tid = threadIdx.x, lane = tid & 63, wv = tid >> 6;
  const int col = lane & 31, half = lane >> 5;
  const int t0 = tg * TILE_T;
  const int piBeg = P.start[g], np = P.start[g + 1] - piBeg;

  f32x16 acc[NTILE];
  #pragma unroll
  for (int t = 0; t < NTILE; ++t)
    #pragma unroll
    for (int i = 0; i < 16; ++i) acc[t][i] = 0.0f;

  if (np > 0) {
    const int c = P.c[piBeg], ka = P.ka[piBeg];
    const int off = gidx[(size_t)c * T] - (K - 1);
    const int s = off & 7;
    const int X0a = t0 + off + ka - s;
    issue_piece(xhp, xlp, whlp,
                (b * NUMCH + c) * rowdw + ((PL + X0a) >> 1),
                c * wrow + 32 + ka - s, smem, wv, lane);
  }
  for (int idx = 0; idx < np; ++idx) {
    __syncthreads();   // drains DMA(idx) (issued a full piece of compute ago)
    if (idx + 1 < np) {
      const int pi = piBeg + idx + 1;
      const int c = P.c[pi], ka = P.ka[pi];
      const int off = gidx[(size_t)c * T] - (K - 1);
      const int s = off & 7;
      const int X0a = t0 + off + ka - s;
      issue_piece(xhp, xlp, whlp,
                  (b * NUMCH + c) * rowdw + ((PL + X0a) >> 1),
                  c * wrow + 32 + ka - s, smem + ((idx + 1) & 1) * BUFDW, wv, lane);
    }
    uint32_t* buf = smem + (idx & 1) * BUFDW;
    compute_piece(P.nc[piBeg + idx], buf, buf + XPLANE, buf + 2 * XPLANE, acc, col, half, wv);
  }

  __syncthreads();
  const float inv_fs = 1.0f / (float)fsp[0];
  epilogue(smem, acc, out, (size_t)b * T + t0, inv_fs, tid, col, half, wv);
}

// ---- fallback (ws too small): VALU staging, single buffer, same math ----
__global__ __launch_bounds__(THREADS, 4)
void conv_fb(const float* __restrict__ inp, const float* __restrict__ wgt,
             const int* __restrict__ gidx, const int* __restrict__ fsp,
             float* __restrict__ out, PTab P, int B, int T, int K)
{
  __shared__ __align__(16) uint32_t smem[SMEMDW];
  uint32_t* bxh = smem;
  uint32_t* bxl = smem + XPLANE;
  uint32_t* bwb = smem + 2 * XPLANE;
  const int g = blockIdx.x, tg = blockIdx.y, b = blockIdx.z;
  const int tid = threadIdx.x, lane = tid & 63, wv = tid >> 6;
  const int col = lane & 31, half = lane >> 5;
  const int t0 = tg * TILE_T;
  const int piBeg = P.start[g], piEnd = P.start[g + 1];

  f32x16 acc[NTILE];
  #pragma unroll
  for (int t = 0; t < NTILE; ++t)
    #pragma unroll
    for (int i = 0; i < 16; ++i) acc[t][i] = 0.0f;

  for (int pi = piBeg; pi < piEnd; ++pi) {
    const int c = P.c[pi], ka = P.ka[pi], nc = P.nc[pi];
    const int off = gidx[(size_t)c * T] - (K - 1);
    const int s = off & 7;
    const int X0a = t0 + off + ka - s;
    const int ka2m32 = ka - s - 32;
    const float* __restrict__ xc = inp + ((size_t)b * (2 * NUMCH) + c) * T;
    const float* __restrict__ wc = wgt + (size_t)c * K;
    __syncthreads();
    for (int d = tid; d < XDW; d += THREADS) {
      const int e0 = X0a + 2 * d;
      const float v0 = (e0 >= 0 && e0 < T) ? xc[e0] : 0.0f;
      const float v1 = (e0 + 1 >= 0 && e0 + 1 < T) ? xc[e0 + 1] : 0.0f;
      uint32_t h0, l0, h1, l1;
      splithl(v0, h0, l0);
      splithl(v1, h1, l1);
      const int pd = d + ((d >> 5) << 2);
      bxh[pd] = h0 | (h1 << 16);
      bxl[pd] = l0 | (l1 << 16);
    }
    for (int d = tid; d < WBDW; d += THREADS) {
      const int k = ka2m32 + d;
      bwb[d] = packhl((k >= 0 && k < K) ? wc[k] : 0.0f);
    }
    __syncthreads();
    compute_piece(nc, bxh, bxl, bwb, acc, col, half, wv);
  }
  __syncthreads();
  const float inv_fs = 1.0f / (float)fsp[0];
  epilogue(smem, acc, out, (size_t)b * T + t0, inv_fs, tid, col, half, wv);
}

extern "C" void kernel_launch(void* const* d_in, const int* in_sizes, int n_in,
                              void* d_out, int out_size, void* d_ws, size_t ws_size,
                              hipStream_t stream)
{
  const float* inp = (const float*)d_in[0];
  const float* wgt = (const float*)d_in[1];
  const int* gidx  = (const int*)d_in[2];
  const int* fsp   = (const int*)d_in[3];
  float* out = (float*)d_out;

  const int K = in_sizes[1] / NUMCH;
  const int T = in_sizes[2] / NUMCH;
  const int B = in_sizes[0] / (2 * NUMCH * T);

  // scratch plane geometry
  const int PL = ((K / 10) + 80 + 7) & ~7;              // low pad (>= max aline + slack)
  const int PH = K - K / 10 + 1024;                     // high pad (>= max start_c + fetch slack)
  const int rowstride = (PL + T + PH + 7) & ~7;
  const int rowdw = rowstride >> 1;
  const int wrow = K + 960;
  const size_t planeDw = (size_t)rowdw * (NUMCH * B);
  const size_t need = 2 * planeDw * 4 + (size_t)wrow * NUMCH * 4;

  // ---- exact-partition piece table (analytic gammatone lengths) ----
  const double a = pow(10.0, 1.0 / 32.0);
  int pC[MAXP], pKa[MAXP], pNc[MAXP];
  double pW[MAXP];
  int np_ = 0;
  for (int c = 0; c < NUMCH; ++c) {
    int gl = (int)ceil((K / 10.0) * pow(a, 32.0 - c) - 1e-9);
    if (gl > K) gl = K;
    int k0 = K - gl - 48; if (k0 < 0) k0 = 0;
    k0 &= ~15;
    const int len = K - k0;
    const int npc = (len + PLEN - 1) / PLEN;
    int plen = (((len + npc - 1) / npc) + 15) & ~15;
    for (int i = 0; i < npc && np_ < MAXP; ++i) {
      const int kai = k0 + i * plen;
      if (kai >= K) break;
      int nc;
      if (i == npc - 1 || kai + plen >= K) nc = (K - kai + 38 + 15) / 16;  // last: +shift margin
      else nc = plen / 16;                                                  // interior: exact
      if (nc > NCMAX) nc = NCMAX;
      pC[np_] = c; pKa[np_] = kai; pNc[np_] = nc;
      pW[np_] = (double)nc + 4.0;
      ++np_;
    }
  }
  // sort by descending work, greedy LPT into NGRP groups
  for (int i = 1; i < np_; ++i) {
    int c = pC[i], ka = pKa[i], nc = pNc[i];
    double wv = pW[i];
    int j = i - 1;
    while (j >= 0 && pW[j] < wv) {
      pC[j+1]=pC[j]; pKa[j+1]=pKa[j]; pNc[j+1]=pNc[j]; pW[j+1]=pW[j]; --j;
    }
    pC[j+1]=c; pKa[j+1]=ka; pNc[j+1]=nc; pW[j+1]=wv;
  }
  double gsum[NGRP]; int gcnt[NGRP];
  static int glist[NGRP][MAXP];
  for (int g = 0; g < NGRP; ++g) { gsum[g] = 0.0; gcnt[g] = 0; }
  for (int i = 0; i < np_; ++i) {
    int best = 0;
    for (int g = 1; g < NGRP; ++g) if (gsum[g] < gsum[best]) best = g;
    glist[best][gcnt[best]++] = i;
    gsum[best] += pW[i];
  }
  PTab P;
  int p = 0;
  P.start[0] = 0;
  for (int g = 0; g < NGRP; ++g) {
    for (int i = 0; i < gcnt[g]; ++i) {
      const int id = glist[g][i];
      P.c[p] = (short)pC[id]; P.ka[p] = (short)pKa[id]; P.nc[p] = (short)pNc[id];
      ++p;
    }
    P.start[g + 1] = p;
  }
  for (int i = p; i < MAXP; ++i) { P.c[i] = 0; P.ka[i] = 0; P.nc[i] = 0; }

  zero_kernel<<<(out_size + 255) / 256, 256, 0, stream>>>(out, out_size);
  dim3 grid(NGRP, T / TILE_T, B);

  if (ws_size >= need) {
    uint32_t* xhp = (uint32_t*)d_ws;
    uint32_t* xlp = xhp + planeDw;
    uint32_t* whlp = xlp + planeDw;
    dim3 gx((rowdw + 255) / 256, NUMCH * B);
    prep_x<<<gx, 256, 0, stream>>>(inp, xhp, xlp, T, rowdw, PL);
    dim3 gw((wrow + 255) / 256, NUMCH);
    prep_w<<<gw, 256, 0, stream>>>(wgt, whlp, K, wrow);
    conv_dma<<<grid, THREADS, 0, stream>>>(xhp, xlp, whlp, gidx, fsp, out, P,
                                           B, T, K, rowdw, wrow, PL);
  } else {
    conv_fb<<<grid, THREADS, 0, stream>>>(inp, wgt, gidx, fsp, out, P, B, T, K);
  }
}

// Round 8
// 197.856 us; speedup vs baseline: 1.0045x; 1.0045x over previous
//
#include <hip/hip_runtime.h>
#include <math.h>
#include <stdint.h>

#define NUMCH 65
#define THREADS 256
#define WAVES 4
#define NTILE 4
#define CTILE 1024
#define TILE_T 4096
#define NGRP 48
#define PLEN 544
#define MAXP 320
#define NCMAX 38

// LDS geometry (dwords)
#define XDW 2368        // logical x-window dwords (2 bf16 el/dword)
#define XPLANE 2816     // phys (SW4-swizzled) plane, 11*256
#define XINSTS 11       // width-16 DMA insts per plane
#define UMAX 664        // last valid phys 16B slot
#define WBDW 704        // w-band dwords (11*64)
#define WINSTS 11
#define BUFDW (2 * XPLANE + WBDW)   // 6336
#define SMEMDW (2 * BUFDW)          // 12672 dw = 50.7 KB
#define RSTRIDE 1184

struct PTab {
  short c[MAXP], ka[MAXP], nc[MAXP];
  int start[NGRP + 1];
};

typedef short bf16x8 __attribute__((ext_vector_type(8)));
typedef float f32x16 __attribute__((ext_vector_type(16)));
typedef const __attribute__((address_space(1))) uint32_t* gptr_t;
typedef __attribute__((address_space(3))) uint32_t* sptr_t;

__device__ __forceinline__ uint32_t f2bf(float f) {
  uint32_t u = __float_as_uint(f);
  return (u + 0x7FFFu + ((u >> 16) & 1u)) >> 16;
}
__device__ __forceinline__ void splithl(float v, uint32_t& h, uint32_t& l) {
  h = f2bf(v);
  l = f2bf(v - __uint_as_float(h << 16));
}
__device__ __forceinline__ uint32_t packhl(float v) {
  uint32_t h, l;
  splithl(v, h, l);
  return h | (l << 16);
}

// ---- phase 1: precompute bf16 h/l planes for x (zero-padded margins) ----
__global__ void prep_x(const float* __restrict__ inp, uint32_t* __restrict__ xh,
                       uint32_t* __restrict__ xl, int T, int rowdw, int PL)
{
  const int row = blockIdx.y;                               // b*65+c
  const int d = blockIdx.x * blockDim.x + threadIdx.x;
  if (d >= rowdw) return;
  const int b = row / NUMCH, c = row % NUMCH;
  const float* xr = inp + ((size_t)b * (2 * NUMCH) + c) * T;
  const int t0 = 2 * d - PL;
  const float v0 = (t0 >= 0 && t0 < T) ? xr[t0] : 0.0f;
  const float v1 = (t0 + 1 >= 0 && t0 + 1 < T) ? xr[t0 + 1] : 0.0f;
  uint32_t h0, l0, h1, l1;
  splithl(v0, h0, l0);
  splithl(v1, h1, l1);
  xh[(size_t)row * rowdw + d] = h0 | (h1 << 16);
  xl[(size_t)row * rowdw + d] = l0 | (l1 << 16);
}

// ---- phase 1: w -> hl dword plane (zero-padded) ----
__global__ void prep_w(const float* __restrict__ w, uint32_t* __restrict__ whl, int K, int wrow)
{
  const int i = blockIdx.x * blockDim.x + threadIdx.x;
  const int c = blockIdx.y;
  if (i >= wrow) return;
  const int k = i - 64;
  const float v = (k >= 0 && k < K) ? w[(size_t)c * K + k] : 0.0f;
  whl[(size_t)c * wrow + i] = packhl(v);
}

// ---- async DMA staging of one piece into an LDS buffer ----
__device__ __forceinline__ void issue_piece(const uint32_t* __restrict__ xhp,
                                            const uint32_t* __restrict__ xlp,
                                            const uint32_t* __restrict__ whlp,
                                            int xbase, int wq0, uint32_t* buf,
                                            int wv, int lane)
{
  uint32_t* bxh = buf;
  uint32_t* bxl = buf + XPLANE;
  uint32_t* bwb = buf + 2 * XPLANE;
  #pragma unroll
  for (int i = 0; i < XINSTS; ++i) {
    if ((i & 3) != wv) continue;                 // round-robin insts over waves
    int u = 64 * i + lane;
    if (u > UMAX) u = UMAX;
    const int m = u - (u + 1) / 9;               // phys 16B slot -> logical 16B group
    __builtin_amdgcn_global_load_lds((gptr_t)(xhp + xbase + 4 * m), (sptr_t)(bxh + 256 * i), 16, 0, 0);
    __builtin_amdgcn_global_load_lds((gptr_t)(xlp + xbase + 4 * m), (sptr_t)(bxl + 256 * i), 16, 0, 0);
  }
  #pragma unroll
  for (int i = 0; i < WINSTS; ++i) {
    if ((i & 3) != wv) continue;
    const int d = 64 * i + lane;
    __builtin_amdgcn_global_load_lds((gptr_t)(whlp + wq0 + d), (sptr_t)(bwb + 64 * i), 4, 0, 0);
  }
}

// ---- MFMA inner loop over one staged piece ----
__device__ __forceinline__ void compute_piece(int nc, const uint32_t* bxh, const uint32_t* bxl,
                                              const uint32_t* bwb, f32x16* acc,
                                              int col, int half, int wv)
{
  for (int ci = wv; ci < nc; ci += WAVES) {
    const int abase = 32 + 16 * ci + 8 * half - col;
    uint32_t ad[8];
    #pragma unroll
    for (int j = 0; j < 8; ++j) ad[j] = bwb[abase + j];
    union AU { uint32_t u[4]; bf16x8 v; } Ah, Al;
    #pragma unroll
    for (int j = 0; j < 4; ++j) {
      const uint32_t a0 = ad[2 * j], a1 = ad[2 * j + 1];
      Ah.u[j] = (a0 & 0xFFFFu) | (a1 << 16);
      Al.u[j] = (a0 >> 16) | (a1 & 0xFFFF0000u);
    }
    const int dbase = 16 * col + 8 * ci + 4 * half;
    #pragma unroll
    for (int tau = 0; tau < NTILE; ++tau) {
      const int d0 = 512 * tau + dbase;
      const int p0 = d0 + ((d0 >> 5) << 2);      // SW4
      union BU { uint4 q; bf16x8 v; } Bh, Bl;
      Bh.q = *(const uint4*)&bxh[p0];
      Bl.q = *(const uint4*)&bxl[p0];
      acc[tau] = __builtin_amdgcn_mfma_f32_32x32x16_bf16(Ah.v, Bh.v, acc[tau], 0, 0, 0);
      acc[tau] = __builtin_amdgcn_mfma_f32_32x32x16_bf16(Ah.v, Bl.v, acc[tau], 0, 0, 0);
      acc[tau] = __builtin_amdgcn_mfma_f32_32x32x16_bf16(Al.v, Bh.v, acc[tau], 0, 0, 0);
    }
  }
}

__device__ __forceinline__ void epilogue(uint32_t* smem, f32x16* acc, float* __restrict__ out,
                                         size_t outbase, float inv_fs, int tid, int col, int half, int wv)
{
  #pragma unroll
  for (int tau = 0; tau < NTILE; ++tau) {
    #pragma unroll
    for (int r = 0; r < 16; ++r) {
      const int row = (r & 3) + 8 * (r >> 2) + 4 * half;   // verified C/D layout
      const int tl = 32 * col + row;
      smem[wv * RSTRIDE + tl + (tl >> 5) * 5] = __float_as_uint(acc[tau][r]);
    }
    __syncthreads();
    for (int i = tid; i < CTILE; i += THREADS) {
      const int p = i + (i >> 5) * 5;
      float s = __uint_as_float(smem[p]) + __uint_as_float(smem[RSTRIDE + p]) +
                __uint_as_float(smem[2 * RSTRIDE + p]) + __uint_as_float(smem[3 * RSTRIDE + p]);
      atomicAdd(&out[outbase + tau * CTILE + i], s * inv_fs);
    }
    __syncthreads();
  }
}

// ---- main kernel: DMA-staged, double-buffered ----
__global__ __launch_bounds__(THREADS, 3)
void conv_dma(const uint32_t* __restrict__ xhp, const uint32_t* __restrict__ xlp,
              const uint32_t* __restrict__ whlp, const int* __restrict__ gidx,
              const int* __restrict__ fsp, float* __restrict__ out, PTab P,
              int B, int T, int K, int rowdw, int wrow, int PL)
{
  __shared__ __align__(16) uint32_t smem[SMEMDW];
  const int g = blockIdx.x, tg = blockIdx.y, b = blockIdx.z;
  const int tid = threadIdx.x, lane = tid & 63, wv = tid >> 6;
  const int col = lane & 31, half = lane >> 5;
  const int t0 = tg * TILE_T;
  const int piBeg = P.start[g], np = P.start[g + 1] - piBeg;

  f32x16 acc[NTILE];
  #pragma unroll
  for (int t = 0; t < NTILE; ++t)
    #pragma unroll
    for (int i = 0; i < 16; ++i) acc[t][i] = 0.0f;

  if (np > 0) {
    const int c = P.c[piBeg], ka = P.ka[piBeg];
    const int off = gidx[(size_t)c * T] - (K - 1);
    const int s = off & 7;
    const int X0a = t0 + off + ka - s;
    issue_piece(xhp, xlp, whlp,
                (b * NUMCH + c) * rowdw + ((PL + X0a) >> 1),
                c * wrow + 32 + ka - s, smem, wv, lane);
  }
  for (int idx = 0; idx < np; ++idx) {
    __syncthreads();   // drains DMA(idx) (issued a full piece of compute ago)
    if (idx + 1 < np) {
      const int pi = piBeg + idx + 1;
      const int c = P.c[pi], ka = P.ka[pi];
      const int off = gidx[(size_t)c * T] - (K - 1);
      const int s = off & 7;
      const int X0a = t0 + off + ka - s;
      issue_piece(xhp, xlp, whlp,
                  (b * NUMCH + c) * rowdw + ((PL + X0a) >> 1),
                  c * wrow + 32 + ka - s, smem + ((idx + 1) & 1) * BUFDW, wv, lane);
    }
    uint32_t* buf = smem + (idx & 1) * BUFDW;
    compute_piece(P.nc[piBeg + idx], buf, buf + XPLANE, buf + 2 * XPLANE, acc, col, half, wv);
  }

  __syncthreads();
  const float inv_fs = 1.0f / (float)fsp[0];
  epilogue(smem, acc, out, (size_t)b * T + t0, inv_fs, tid, col, half, wv);
}

// ---- fallback (ws too small): VALU staging, single buffer, same math ----
__global__ __launch_bounds__(THREADS, 3)
void conv_fb(const float* __restrict__ inp, const float* __restrict__ wgt,
             const int* __restrict__ gidx, const int* __restrict__ fsp,
             float* __restrict__ out, PTab P, int B, int T, int K)
{
  __shared__ __align__(16) uint32_t smem[SMEMDW];
  uint32_t* bxh = smem;
  uint32_t* bxl = smem + XPLANE;
  uint32_t* bwb = smem + 2 * XPLANE;
  const int g = blockIdx.x, tg = blockIdx.y, b = blockIdx.z;
  const int tid = threadIdx.x, lane = tid & 63, wv = tid >> 6;
  const int col = lane & 31, half = lane >> 5;
  const int t0 = tg * TILE_T;
  const int piBeg = P.start[g], piEnd = P.start[g + 1];

  f32x16 acc[NTILE];
  #pragma unroll
  for (int t = 0; t < NTILE; ++t)
    #pragma unroll
    for (int i = 0; i < 16; ++i) acc[t][i] = 0.0f;

  for (int pi = piBeg; pi < piEnd; ++pi) {
    const int c = P.c[pi], ka = P.ka[pi], nc = P.nc[pi];
    const int off = gidx[(size_t)c * T] - (K - 1);
    const int s = off & 7;
    const int X0a = t0 + off + ka - s;
    const int ka2m32 = ka - s - 32;
    const float* __restrict__ xc = inp + ((size_t)b * (2 * NUMCH) + c) * T;
    const float* __restrict__ wc = wgt + (size_t)c * K;
    __syncthreads();
    for (int d = tid; d < XDW; d += THREADS) {
      const int e0 = X0a + 2 * d;
      const float v0 = (e0 >= 0 && e0 < T) ? xc[e0] : 0.0f;
      const float v1 = (e0 + 1 >= 0 && e0 + 1 < T) ? xc[e0 + 1] : 0.0f;
      uint32_t h0, l0, h1, l1;
      splithl(v0, h0, l0);
      splithl(v1, h1, l1);
      const int pd = d + ((d >> 5) << 2);
      bxh[pd] = h0 | (h1 << 16);
      bxl[pd] = l0 | (l1 << 16);
    }
    for (int d = tid; d < WBDW; d += THREADS) {
      const int k = ka2m32 + d;
      bwb[d] = packhl((k >= 0 && k < K) ? wc[k] : 0.0f);
    }
    __syncthreads();
    compute_piece(nc, bxh, bxl, bwb, acc, col, half, wv);
  }
  __syncthreads();
  const float inv_fs = 1.0f / (float)fsp[0];
  epilogue(smem, acc, out, (size_t)b * T + t0, inv_fs, tid, col, half, wv);
}

extern "C" void kernel_launch(void* const* d_in, const int* in_sizes, int n_in,
                              void* d_out, int out_size, void* d_ws, size_t ws_size,
                              hipStream_t stream)
{
  const float* inp = (const float*)d_in[0];
  const float* wgt = (const float*)d_in[1];
  const int* gidx  = (const int*)d_in[2];
  const int* fsp   = (const int*)d_in[3];
  float* out = (float*)d_out;

  const int K = in_sizes[1] / NUMCH;
  const int T = in_sizes[2] / NUMCH;
  const int B = in_sizes[0] / (2 * NUMCH * T);

  // scratch plane geometry
  const int PL = ((K / 10) + 80 + 7) & ~7;              // low pad (>= max aline + slack)
  const int PH = K - K / 10 + 1024;                     // high pad
  const int rowstride = (PL + T + PH + 7) & ~7;
  const int rowdw = rowstride >> 1;
  const int wrow = K + 960;
  const size_t planeDw = (size_t)rowdw * (NUMCH * B);
  const size_t need = 2 * planeDw * 4 + (size_t)wrow * NUMCH * 4;

  // ---- exact-partition piece table (analytic gammatone lengths) ----
  const double a = pow(10.0, 1.0 / 32.0);
  int pC[MAXP], pKa[MAXP], pNc[MAXP];
  double pW[MAXP];
  int np_ = 0;
  for (int c = 0; c < NUMCH; ++c) {
    int gl = (int)ceil((K / 10.0) * pow(a, 32.0 - c) - 1e-9);
    if (gl > K) gl = K;
    int k0 = K - gl - 48; if (k0 < 0) k0 = 0;
    k0 &= ~15;
    const int len = K - k0;
    const int npc = (len + PLEN - 1) / PLEN;
    int plen = (((len + npc - 1) / npc) + 15) & ~15;
    for (int i = 0; i < npc && np_ < MAXP; ++i) {
      const int kai = k0 + i * plen;
      if (kai >= K) break;
      int nc;
      if (i == npc - 1 || kai + plen >= K) nc = (K - kai + 38 + 15) / 16;  // last: +shift margin
      else nc = plen / 16;                                                  // interior: exact
      if (nc > NCMAX) nc = NCMAX;
      pC[np_] = c; pKa[np_] = kai; pNc[np_] = nc;
      pW[np_] = (double)nc + 4.0;
      ++np_;
    }
  }
  // sort by descending work, greedy LPT into NGRP groups
  for (int i = 1; i < np_; ++i) {
    int c = pC[i], ka = pKa[i], nc = pNc[i];
    double wv = pW[i];
    int j = i - 1;
    while (j >= 0 && pW[j] < wv) {
      pC[j+1]=pC[j]; pKa[j+1]=pKa[j]; pNc[j+1]=pNc[j]; pW[j+1]=pW[j]; --j;
    }
    pC[j+1]=c; pKa[j+1]=ka; pNc[j+1]=nc; pW[j+1]=wv;
  }
  double gsum[NGRP]; int gcnt[NGRP];
  static int glist[NGRP][MAXP];
  for (int g = 0; g < NGRP; ++g) { gsum[g] = 0.0; gcnt[g] = 0; }
  for (int i = 0; i < np_; ++i) {
    int best = 0;
    for (int g = 1; g < NGRP; ++g) if (gsum[g] < gsum[best]) best = g;
    glist[best][gcnt[best]++] = i;
    gsum[best] += pW[i];
  }
  PTab P;
  int p = 0;
  P.start[0] = 0;
  for (int g = 0; g < NGRP; ++g) {
    for (int i = 0; i < gcnt[g]; ++i) {
      const int id = glist[g][i];
      P.c[p] = (short)pC[id]; P.ka[p] = (short)pKa[id]; P.nc[p] = (short)pNc[id];
      ++p;
    }
    P.start[g + 1] = p;
  }
  for (int i = p; i < MAXP; ++i) { P.c[i] = 0; P.ka[i] = 0; P.nc[i] = 0; }

  hipMemsetAsync(out, 0, (size_t)out_size * sizeof(float), stream);
  dim3 grid(NGRP, T / TILE_T, B);

  if (ws_size >= need) {
    uint32_t* xhp = (uint32_t*)d_ws;
    uint32_t* xlp = xhp + planeDw;
    uint32_t* whlp = xlp + planeDw;
    dim3 gx((rowdw + 255) / 256, NUMCH * B);
    prep_x<<<gx, 256, 0, stream>>>(inp, xhp, xlp, T, rowdw, PL);
    dim3 gw((wrow + 255) / 256, NUMCH);
    prep_w<<<gw, 256, 0, stream>>>(wgt, whlp, K, wrow);
    conv_dma<<<grid, THREADS, 0, stream>>>(xhp, xlp, whlp, gidx, fsp, out, P,
                                           B, T, K, rowdw, wrow, PL);
  } else {
    conv_fb<<<grid, THREADS, 0, stream>>>(inp, wgt, gidx, fsp, out, P, B, T, K);
  }
}